// Round 1
// baseline (138.716 us; speedup 1.0000x reference)
//
#include <hip/hip_runtime.h>

// GaussianBlur 3x3, sigma=0 -> separable [0.25, 0.5, 0.25], BORDER_REFLECT_101.
// Input/output: float32 [64, 3, 512, 512]. Memory-bound: fuse both passes,
// one float4 of output per thread.

#define HH 512
#define WW 512
#define W4G 128  // WW / 4 float4-groups per row

__global__ __launch_bounds__(256) void gauss3_kernel(const float* __restrict__ in,
                                                     float* __restrict__ out,
                                                     int n_groups) {
    int idx = blockIdx.x * 256 + threadIdx.x;
    if (idx >= n_groups) return;

    int w4    = idx & (W4G - 1);        // float4-group within row
    int h     = (idx >> 7) & (HH - 1);  // row
    int plane = idx >> 16;              // (b, c) plane: 128*512 = 65536 groups/plane

    const float* p = in  + (size_t)plane * (HH * WW);
    float*       q = out + (size_t)plane * (HH * WW);

    // reflect-101 vertical neighbors
    int hm = (h == 0)      ? 1      : h - 1;
    int hp = (h == HH - 1) ? HH - 2 : h + 1;

    const float* rm = p + (size_t)hm * WW;
    const float* r0 = p + (size_t)h  * WW;
    const float* rp = p + (size_t)hp * WW;

    int w0 = w4 << 2;

    float4 am = *(const float4*)(rm + w0);
    float4 a0 = *(const float4*)(r0 + w0);
    float4 ap = *(const float4*)(rp + w0);

    // vertical blur of the 4 main columns
    float4 v;
    v.x = 0.25f * (am.x + ap.x) + 0.5f * a0.x;
    v.y = 0.25f * (am.y + ap.y) + 0.5f * a0.y;
    v.z = 0.25f * (am.z + ap.z) + 0.5f * a0.z;
    v.w = 0.25f * (am.w + ap.w) + 0.5f * a0.w;

    // vertical blur of the horizontal edge neighbors (w0-1, w0+4),
    // with reflect-101 at the W boundaries.
    float vl, vr;
    if (w0 == 0) {
        vl = v.y;  // reflect: in[-1] == in[1]
    } else {
        vl = 0.25f * (rm[w0 - 1] + rp[w0 - 1]) + 0.5f * r0[w0 - 1];
    }
    if (w0 + 4 == WW) {
        vr = v.z;  // reflect: in[512] == in[510] (== .z of last group)
    } else {
        vr = 0.25f * (rm[w0 + 4] + rp[w0 + 4]) + 0.5f * r0[w0 + 4];
    }

    // horizontal blur
    float4 o;
    o.x = 0.25f * (vl  + v.y) + 0.5f * v.x;
    o.y = 0.25f * (v.x + v.z) + 0.5f * v.y;
    o.z = 0.25f * (v.y + v.w) + 0.5f * v.z;
    o.w = 0.25f * (v.z + vr ) + 0.5f * v.w;

    *(float4*)(q + (size_t)h * WW + w0) = o;
}

extern "C" void kernel_launch(void* const* d_in, const int* in_sizes, int n_in,
                              void* d_out, int out_size, void* d_ws, size_t ws_size,
                              hipStream_t stream) {
    const float* x   = (const float*)d_in[0];
    float*       out = (float*)d_out;

    int n        = in_sizes[0];   // 64*3*512*512 = 50331648
    int n_groups = n >> 2;        // float4 groups
    int blocks   = (n_groups + 255) / 256;

    gauss3_kernel<<<blocks, 256, 0, stream>>>(x, out, n_groups);
}

// Round 2
// 80.780 us; speedup vs baseline: 1.7172x; 1.7172x over previous
//
#include <hip/hip_runtime.h>

// GaussianBlur 3x3 sigma=0 -> separable [0.25,0.5,0.25], BORDER_REFLECT_101.
// f32 [64,3,512,512]. One wave (64 lanes x 8 px) covers one full 512-px row;
// each thread produces 8 px in each of 2 consecutive rows. Horizontal edge
// neighbors come from adjacent lanes via shuffle -> zero scalar loads.

#define HH 512
#define WW 512

#define VBLUR(d, m, c, pq)                         \
    d.x = 0.25f * (m.x + pq.x) + 0.5f * c.x;       \
    d.y = 0.25f * (m.y + pq.y) + 0.5f * c.y;       \
    d.z = 0.25f * (m.z + pq.z) + 0.5f * c.z;       \
    d.w = 0.25f * (m.w + pq.w) + 0.5f * c.w;

#define HBLUR(oa, ob, ua, ub, l, r)                        \
    oa.x = 0.25f * (l    + ua.y) + 0.5f * ua.x;            \
    oa.y = 0.25f * (ua.x + ua.z) + 0.5f * ua.y;            \
    oa.z = 0.25f * (ua.y + ua.w) + 0.5f * ua.z;            \
    oa.w = 0.25f * (ua.z + ub.x) + 0.5f * ua.w;            \
    ob.x = 0.25f * (ua.w + ub.y) + 0.5f * ub.x;            \
    ob.y = 0.25f * (ub.x + ub.z) + 0.5f * ub.y;            \
    ob.z = 0.25f * (ub.y + ub.w) + 0.5f * ub.z;            \
    ob.w = 0.25f * (ub.z + r   ) + 0.5f * ub.w;

__global__ __launch_bounds__(256) void gauss3_kernel(const float* __restrict__ in,
                                                     float* __restrict__ out) {
    int wid  = (blockIdx.x * 256 + threadIdx.x) >> 6;  // global wave id
    int lane = threadIdx.x & 63;

    int rowpair = wid & 255;   // 256 row-pairs per (b,c) plane
    int plane   = wid >> 8;

    int h0 = rowpair << 1;
    int h1 = h0 + 1;
    int hm = (h0 == 0)      ? 1      : h0 - 1;   // reflect-101
    int hp = (h1 == HH - 1) ? HH - 2 : h1 + 1;   // reflect-101

    const float* p = in  + (size_t)plane * (HH * WW);
    float*       q = out + (size_t)plane * (HH * WW);
    int w0 = lane << 3;  // 8 px per lane

    const float4* Lm = (const float4*)(p + (size_t)hm * WW + w0);
    const float4* L0 = (const float4*)(p + (size_t)h0 * WW + w0);
    const float4* L1 = (const float4*)(p + (size_t)h1 * WW + w0);
    const float4* Lp = (const float4*)(p + (size_t)hp * WW + w0);

    // 8 wide loads up front (MLP)
    float4 am0 = Lm[0], am1 = Lm[1];
    float4 a00 = L0[0], a01 = L0[1];
    float4 a10 = L1[0], a11 = L1[1];
    float4 ap0 = Lp[0], ap1 = Lp[1];

    // vertical blur: row h0 uses (hm, h0, h1); row h1 uses (h0, h1, hp)
    float4 u0a, u0b, u1a, u1b;
    VBLUR(u0a, am0, a00, a10)
    VBLUR(u0b, am1, a01, a11)
    VBLUR(u1a, a00, a10, ap0)
    VBLUR(u1b, a01, a11, ap1)

    // horizontal edge neighbors from adjacent lanes
    float l0 = __shfl_up(u0b.w, 1);
    float l1 = __shfl_up(u1b.w, 1);
    float r0 = __shfl_down(u0a.x, 1);
    float r1 = __shfl_down(u1a.x, 1);
    if (lane == 0)  { l0 = u0a.y; l1 = u1a.y; }   // reflect: in[-1] == in[1]
    if (lane == 63) { r0 = u0b.z; r1 = u1b.z; }   // reflect: in[512] == in[510]

    float4 o0a, o0b, o1a, o1b;
    HBLUR(o0a, o0b, u0a, u0b, l0, r0)
    HBLUR(o1a, o1b, u1a, u1b, l1, r1)

    float4* S0 = (float4*)(q + (size_t)h0 * WW + w0);
    float4* S1 = (float4*)(q + (size_t)h1 * WW + w0);
    S0[0] = o0a; S0[1] = o0b;
    S1[0] = o1a; S1[1] = o1b;
}

extern "C" void kernel_launch(void* const* d_in, const int* in_sizes, int n_in,
                              void* d_out, int out_size, void* d_ws, size_t ws_size,
                              hipStream_t stream) {
    const float* x   = (const float*)d_in[0];
    float*       out = (float*)d_out;

    int n      = in_sizes[0];          // 64*3*512*512
    int planes = n / (HH * WW);        // 192
    int waves  = planes * (HH / 2);    // one wave per row-pair: 49152
    int blocks = waves / 4;            // 4 waves per 256-thread block: 12288

    gauss3_kernel<<<blocks, 256, 0, stream>>>(x, out);
}

// Round 4
// 76.402 us; speedup vs baseline: 1.8156x; 1.0573x over previous
//
#include <hip/hip_runtime.h>

// GaussianBlur 3x3 sigma=0 -> separable [0.25,0.5,0.25], BORDER_REFLECT_101.
// f32 [64,3,512,512]. One wave (64 lanes x 8 px) covers one full 512-px row.
// Each thread produces 8 px in each of 4 consecutive rows (6 input rows
// loaded up front for MLP). Horizontal neighbors via lane shuffles; stores
// are nontemporal so streaming output doesn't evict input halos from L2.

#define HH 512
#define WW 512

// native clang ext-vector: accepted by __builtin_nontemporal_store
typedef float f4 __attribute__((ext_vector_type(4)));

#define VBLUR(d, m, c, pq)                         \
    d.x = 0.25f * (m.x + pq.x) + 0.5f * c.x;       \
    d.y = 0.25f * (m.y + pq.y) + 0.5f * c.y;       \
    d.z = 0.25f * (m.z + pq.z) + 0.5f * c.z;       \
    d.w = 0.25f * (m.w + pq.w) + 0.5f * c.w;

#define HBLUR(oa, ob, ua, ub, l, r)                \
    oa.x = 0.25f * (l    + ua.y) + 0.5f * ua.x;    \
    oa.y = 0.25f * (ua.x + ua.z) + 0.5f * ua.y;    \
    oa.z = 0.25f * (ua.y + ua.w) + 0.5f * ua.z;    \
    oa.w = 0.25f * (ua.z + ub.x) + 0.5f * ua.w;    \
    ob.x = 0.25f * (ua.w + ub.y) + 0.5f * ub.x;    \
    ob.y = 0.25f * (ub.x + ub.z) + 0.5f * ub.y;    \
    ob.z = 0.25f * (ub.y + ub.w) + 0.5f * ub.z;    \
    ob.w = 0.25f * (ub.z + r   ) + 0.5f * ub.w;

// per-row: shuffle edges, reflect at lane 0/63, horizontal blur, NT store
#define ROW_FINISH(ua, ub, h)                                        \
    {                                                                \
        float l = __shfl_up(ub.w, 1);                                \
        float r = __shfl_down(ua.x, 1);                              \
        if (lane == 0)  l = ua.y;                                    \
        if (lane == 63) r = ub.z;                                    \
        f4 oa, ob;                                                   \
        HBLUR(oa, ob, ua, ub, l, r)                                  \
        f4* S = (f4*)(q + (size_t)(h) * WW + w0);                    \
        __builtin_nontemporal_store(oa, S);                          \
        __builtin_nontemporal_store(ob, S + 1);                      \
    }

__global__ __launch_bounds__(256) void gauss3_kernel(const float* __restrict__ in,
                                                     float* __restrict__ out) {
    int wid  = (blockIdx.x * 256 + threadIdx.x) >> 6;  // global wave id
    int lane = threadIdx.x & 63;

    int quad  = wid & 127;   // 128 row-quads per (b,c) plane
    int plane = wid >> 7;

    int h0 = quad << 2;                           // output rows h0 .. h0+3
    int hm = (h0 == 0)       ? 1      : h0 - 1;   // reflect-101
    int hp = (h0 + 4 == HH)  ? HH - 2 : h0 + 4;   // reflect-101

    const float* p = in  + (size_t)plane * (HH * WW);
    float*       q = out + (size_t)plane * (HH * WW);
    int w0 = lane << 3;  // 8 px per lane

    const f4* Lm = (const f4*)(p + (size_t)hm       * WW + w0);
    const f4* L0 = (const f4*)(p + (size_t)h0       * WW + w0);
    const f4* L1 = (const f4*)(p + (size_t)(h0 + 1) * WW + w0);
    const f4* L2 = (const f4*)(p + (size_t)(h0 + 2) * WW + w0);
    const f4* L3 = (const f4*)(p + (size_t)(h0 + 3) * WW + w0);
    const f4* Lp = (const f4*)(p + (size_t)hp       * WW + w0);

    // 12 wide loads up front (MLP)
    f4 ama = Lm[0], amb = Lm[1];
    f4 a0a = L0[0], a0b = L0[1];
    f4 a1a = L1[0], a1b = L1[1];
    f4 a2a = L2[0], a2b = L2[1];
    f4 a3a = L3[0], a3b = L3[1];
    f4 apa = Lp[0], apb = Lp[1];

    // vertical blur per output row, then finish + store
    f4 ua, ub;
    VBLUR(ua, ama, a0a, a1a)  VBLUR(ub, amb, a0b, a1b)
    ROW_FINISH(ua, ub, h0)
    VBLUR(ua, a0a, a1a, a2a)  VBLUR(ub, a0b, a1b, a2b)
    ROW_FINISH(ua, ub, h0 + 1)
    VBLUR(ua, a1a, a2a, a3a)  VBLUR(ub, a1b, a2b, a3b)
    ROW_FINISH(ua, ub, h0 + 2)
    VBLUR(ua, a2a, a3a, apa)  VBLUR(ub, a2b, a3b, apb)
    ROW_FINISH(ua, ub, h0 + 3)
}

extern "C" void kernel_launch(void* const* d_in, const int* in_sizes, int n_in,
                              void* d_out, int out_size, void* d_ws, size_t ws_size,
                              hipStream_t stream) {
    const float* x   = (const float*)d_in[0];
    float*       out = (float*)d_out;

    int n      = in_sizes[0];          // 64*3*512*512
    int planes = n / (HH * WW);        // 192
    int waves  = planes * (HH / 4);    // one wave per row-quad: 24576
    int blocks = waves / 4;            // 4 waves per 256-thread block: 6144

    gauss3_kernel<<<blocks, 256, 0, stream>>>(x, out);
}